// Round 1
// baseline (408.420 us; speedup 1.0000x reference)
//
#include <hip/hip_runtime.h>

typedef unsigned short u16;
typedef __attribute__((ext_vector_type(8))) short bf16x8;   // 8 x bf16 (4 VGPRs)
typedef __attribute__((ext_vector_type(4))) float f32x4;

#define NLEV 5
#define CCH 256
#define KTOT 2304            // 9 taps * 256 ci
#define P_TOT 8525           // sum HW
#define PP_TOT 9165          // sum (H+2)*(W+2)

__constant__ int   c_HW[NLEV]     = {6400, 1600, 400, 100, 25};
__constant__ int   c_W[NLEV]      = {80, 40, 20, 10, 5};
__constant__ int   c_off[NLEV]    = {0, 6400, 8000, 8400, 8500};
__constant__ int   c_poff[NLEV]   = {0, 6724, 8488, 8972, 9116};
__constant__ int   c_pts[NLEV+1]  = {0, 100, 125, 132, 134, 135};   // ptile starts, BN=64
__constant__ float c_stridef[NLEV]= {8.f, 16.f, 32.f, 64.f, 128.f};

__device__ __forceinline__ u16 f2bf(float f){
  union { float f; unsigned u; } v; v.f = f;
  unsigned r = v.u + 0x7fffu + ((v.u >> 16) & 1u);   // RNE
  return (u16)(r >> 16);
}

// async global->LDS, 16B per lane; LDS dst must be wave-uniform base (HW adds lane*16)
__device__ __forceinline__ void g2l16(const u16* g, u16* l, int lane){
#if defined(__has_builtin)
#if __has_builtin(__builtin_amdgcn_global_load_lds)
  __builtin_amdgcn_global_load_lds(
      (const __attribute__((address_space(1))) unsigned int*)g,
      (__attribute__((address_space(3))) unsigned int*)l, 16, 0, 0);
  return;
#endif
#endif
  *(uint4*)(l + lane*8) = *(const uint4*)g;  // fallback: sync copy
}

// ---------------------------------------------------------------------------
// Implicit-GEMM conv 3x3 over padded NHWC bf16 input.
// MODE 0: tower conv (M=256) -> Y fp32 NHWC + GN stats atomics
// MODE 1: heads (z=0: score M=80; z=1: pred+iou M=5) -> packed output [p][85]
// Tile: BM=128 x BN=64 x BK=32. 256 threads = 4 waves, each 32(m) x 64(n).
// ---------------------------------------------------------------------------
template<int MODE>
__global__ __launch_bounds__(256) void gemm_conv(
    const u16* __restrict__ Xc, const u16* __restrict__ Xb,
    const u16* __restrict__ Wc, const u16* __restrict__ Wb,
    const float* __restrict__ bc, const float* __restrict__ bb,
    float* __restrict__ Yc, float* __restrict__ Yb,
    float* __restrict__ stats,
    const float* __restrict__ predb, const float* __restrict__ ioub,
    const float* __restrict__ scales, float* __restrict__ out)
{
  __shared__ u16 sA[128*32];   // [m][k] rows of 64B
  __shared__ u16 sB[64*32];    // [n][k] rows of 64B
  __shared__ float sstat[16][2];

  const int ptile = blockIdx.x, mtile = blockIdx.y, z = blockIdx.z;
  int lv = 0;
  #pragma unroll
  for (int i = 1; i < NLEV; i++) if (ptile >= c_pts[i]) lv = i;
  const int ptl = ptile - c_pts[lv];
  const int HW = c_HW[lv], Wl = c_W[lv];
  const int tid = threadIdx.x, wv = tid >> 6, ln = tid & 63;
  const int quad = ln >> 4, l15 = ln & 15;

  const u16* X  = z ? Xb : Xc;
  const u16* WA = z ? Wb : Wc;

  const int kl   = (ln & 3) * 8;   // element offset within 32-k row
  const int rsub = ln >> 2;        // 0..15: row within a 16-row staging slab

  // A staging: two 1KB slabs per wave (rows wv*32 .. wv*32+31)
  const u16* asrc0 = WA + (size_t)(mtile*128 + wv*32 + rsub) * KTOT + kl;
  const u16* asrc1 = asrc0 + (size_t)16 * KTOT;
  u16* adst0 = &sA[(wv*32)      * 32];
  u16* adst1 = &sA[(wv*32 + 16) * 32];

  // B staging: one 1KB slab per wave (rows wv*16 .. wv*16+15)
  const int prow = wv*16 + rsub;          // n row 0..63
  const int p = ptl*64 + prow;
  int pbase = 0;
  if (p < HW) { int h = p / Wl; int wi = p - h*Wl; pbase = h*(Wl+2) + wi; }
  const u16* bsrc = X + (size_t)(c_poff[lv] + pbase) * CCH + kl;
  u16* bdst = &sB[(wv*16) * 32];

  const u16* afp[2]; const u16* bfp[4];
  #pragma unroll
  for (int i = 0; i < 2; i++) afp[i] = &sA[((wv*32 + i*16 + l15) << 5) + quad*8];
  #pragma unroll
  for (int i = 0; i < 4; i++) bfp[i] = &sB[((i*16 + l15) << 5) + quad*8];

  f32x4 acc[2][4];
  #pragma unroll
  for (int i = 0; i < 2; i++)
    #pragma unroll
    for (int j = 0; j < 4; j++) acc[i][j] = (f32x4){0.f, 0.f, 0.f, 0.f};

  const int wrow = Wl + 2;
  for (int ch = 0; ch < 72; ch++) {          // 9 taps * 8 ci-chunks of 32
    const int tap = ch >> 3;
    const int dh = tap / 3, dw = tap - dh*3;
    const int aoff = ch * 32;                               // k = ch*32 in W layout
    const int boff = (dh*wrow + dw)*CCH + ((ch & 7) << 5);  // tap shift + ci chunk
    g2l16(asrc0 + aoff, adst0, ln);
    g2l16(asrc1 + aoff, adst1, ln);
    g2l16(bsrc + boff, bdst, ln);
    __syncthreads();
    bf16x8 af[2], bfr[4];
    #pragma unroll
    for (int i = 0; i < 2; i++) af[i]  = *(const bf16x8*)afp[i];
    #pragma unroll
    for (int i = 0; i < 4; i++) bfr[i] = *(const bf16x8*)bfp[i];
    #pragma unroll
    for (int i = 0; i < 2; i++)
      #pragma unroll
      for (int j = 0; j < 4; j++)
        acc[i][j] = __builtin_amdgcn_mfma_f32_16x16x32_bf16(af[i], bfr[j], acc[i][j], 0, 0, 0);
    __syncthreads();
  }

  const int nrem = HW - ptl*64;
  if (MODE == 0) {
    if (tid < 32) sstat[tid >> 1][tid & 1] = 0.f;
    __syncthreads();
    const float* bias = z ? bb : bc;
    float* Y = z ? Yb : Yc;
    #pragma unroll
    for (int mi = 0; mi < 2; mi++) {
      const int m0 = mtile*128 + wv*32 + mi*16 + quad*4;
      float s = 0.f, sq = 0.f;
      #pragma unroll
      for (int ni = 0; ni < 4; ni++) {
        const int nl = ni*16 + l15;
        f32x4 v = acc[mi][ni];
        #pragma unroll
        for (int r = 0; r < 4; r++) v[r] += bias[m0 + r];
        if (nl < nrem) {
          const size_t n = (size_t)(c_off[lv] + ptl*64 + nl);
          *(f32x4*)&Y[n*CCH + m0] = v;
          #pragma unroll
          for (int r = 0; r < 4; r++) { s += v[r]; sq += v[r]*v[r]; }
        }
      }
      #pragma unroll
      for (int o = 1; o < 16; o <<= 1) { s += __shfl_xor(s, o); sq += __shfl_xor(sq, o); }
      if (l15 == 0) {
        const int g = (wv*32 + mi*16 + quad*4) >> 3;
        atomicAdd(&sstat[g][0], s);
        atomicAdd(&sstat[g][1], sq);
      }
    }
    __syncthreads();
    if (tid < 32) {
      const int g = tid >> 1, c = tid & 1;
      atomicAdd(&stats[(((size_t)z*NLEV + lv)*32 + mtile*16 + g)*2 + c], sstat[g][c]);
    }
  } else {
    const float scl = scales[lv];
    const float stf = c_stridef[lv];
    #pragma unroll
    for (int mi = 0; mi < 2; mi++) {
      const int m0 = wv*32 + mi*16 + quad*4;
      if (m0 >= 85) continue;
      #pragma unroll
      for (int ni = 0; ni < 4; ni++) {
        const int nl = ni*16 + l15;
        if (nl >= nrem) continue;
        const size_t n = (size_t)(c_off[lv] + ptl*64 + nl);
        f32x4 v = acc[mi][ni];
        #pragma unroll
        for (int r = 0; r < 4; r++) {
          const int m = m0 + r;
          const float val = v[r];
          if (z == 0) {
            if (m < 80) out[n*85 + m] = val + bc[m];           // logits
          } else {
            if (m < 4) {
              const float t = (val + predb[m]) * scl;          // Scale module
              out[n*85 + 80 + m] = fmaxf(t, 0.f) * stf;        // relu * fpn_stride
            } else if (m == 4) {
              out[n*85 + 84] = val + ioub[0];                  // iou
            }
          }
        }
      }
    }
  }
}

// GN finalize + affine + ReLU + bf16 cast into padded NHWC (8 ch / thread)
__global__ __launch_bounds__(256) void gn_relu(
    const float* __restrict__ Yc, const float* __restrict__ Yb,
    const float* __restrict__ stats,
    const float* __restrict__ gwc, const float* __restrict__ gbc,
    const float* __restrict__ gwb, const float* __restrict__ gbb,
    u16* __restrict__ Xc, u16* __restrict__ Xb)
{
  const int t = blockIdx.x * 256 + threadIdx.x;
  if (t >= 2 * P_TOT * 32) return;
  const int br = t / (P_TOT * 32);
  const int r  = t - br * (P_TOT * 32);
  const int pg = r >> 5;
  const int c0 = (r & 31) << 3;
  int lv = 0;
  #pragma unroll
  for (int i = 1; i < NLEV; i++) if (pg >= c_off[i]) lv = i;
  const int pl = pg - c_off[lv];
  const int Wl = c_W[lv];
  const int g = c0 >> 3;
  const float* st = &stats[(((size_t)br*NLEV + lv)*32 + g)*2];
  const float cnt = 8.f * (float)c_HW[lv];
  const float mean = st[0] / cnt;
  const float var  = st[1] / cnt - mean*mean;
  const float rstd = rsqrtf(var + 1e-5f);
  const float* Y  = br ? Yb : Yc;
  const float* gw = br ? gwb : gwc;
  const float* gb = br ? gbb : gbc;
  u16* X = br ? Xb : Xc;
  const float* y = &Y[(size_t)pg*CCH + c0];
  const int h = pl / Wl, wi = pl - h*Wl;
  const size_t pidx = (size_t)(c_poff[lv] + (h+1)*(Wl+2) + (wi+1));
  union { u16 u[8]; uint4 v; } pk;
  #pragma unroll
  for (int i = 0; i < 8; i++) {
    const float v = (y[i] - mean)*rstd*gw[c0+i] + gb[c0+i];
    pk.u[i] = f2bf(fmaxf(v, 0.f));
  }
  *(uint4*)&X[pidx*CCH + c0] = pk.v;
}

// fp32 NCHW feats -> bf16 padded NHWC
__global__ __launch_bounds__(256) void feat2bf(
    const float* __restrict__ p3, const float* __restrict__ p4,
    const float* __restrict__ p5, const float* __restrict__ p6,
    const float* __restrict__ p7, u16* __restrict__ X)
{
  const int t = blockIdx.x * 256 + threadIdx.x;
  if (t >= P_TOT * 32) return;
  const int pg = t >> 5, c0 = (t & 31) << 3;
  int lv = 0;
  #pragma unroll
  for (int i = 1; i < NLEV; i++) if (pg >= c_off[i]) lv = i;
  const int pl = pg - c_off[lv];
  const float* src = lv==0 ? p3 : lv==1 ? p4 : lv==2 ? p5 : lv==3 ? p6 : p7;
  const int HW = c_HW[lv], Wl = c_W[lv];
  const int h = pl / Wl, wi = pl - h*Wl;
  const size_t pidx = (size_t)(c_poff[lv] + (h+1)*(Wl+2) + (wi+1));
  union { u16 u[8]; uint4 v; } pk;
  #pragma unroll
  for (int i = 0; i < 8; i++)
    pk.u[i] = f2bf(src[(size_t)(c0+i)*HW + pl]);
  *(uint4*)&X[pidx*CCH + c0] = pk.v;
}

// tower weights [l][co][ci][9] fp32 -> bf16 [l*256+co][tap*256+ci]
__global__ __launch_bounds__(256) void wconv(
    const float* __restrict__ cw, const float* __restrict__ bw,
    u16* __restrict__ Wc, u16* __restrict__ Wb)
{
  const size_t N = (size_t)4*256*KTOT;
  const size_t t = (size_t)blockIdx.x * 256 + threadIdx.x;
  if (t >= 2*N) return;
  const float* src = (t < N) ? cw : bw;
  u16* dst = (t < N) ? Wc : Wb;
  const size_t i = (t < N) ? t : t - N;
  const size_t lc = i / KTOT;
  const int kk = (int)(i - lc*KTOT);
  const int tap = kk >> 8, ci = kk & 255;
  dst[i] = f2bf(src[(lc*256 + ci)*9 + tap]);
}

// head weights -> bf16 [128 rows padded][tap*256+ci] (cls: 80 rows; box: 4 pred + 1 iou)
__global__ __launch_bounds__(256) void hconv(
    const float* __restrict__ sw, const float* __restrict__ pw,
    const float* __restrict__ iw, u16* __restrict__ Whc, u16* __restrict__ Whb)
{
  const int N = 128 * KTOT;
  const int t = blockIdx.x * 256 + threadIdx.x;
  if (t >= 2*N) return;
  const int i = (t < N) ? t : t - N;
  const int co = i / KTOT, kk = i - co*KTOT;
  const int tap = kk >> 8, ci = kk & 255;
  float v = 0.f;
  if (t < N) {
    if (co < 80) v = sw[(co*256 + ci)*9 + tap];
    Whc[i] = f2bf(v);
  } else {
    if (co < 4)       v = pw[(co*256 + ci)*9 + tap];
    else if (co == 4) v = iw[ci*9 + tap];
    Whb[i] = f2bf(v);
  }
}

extern "C" void kernel_launch(void* const* d_in, const int* in_sizes, int n_in,
                              void* d_out, int out_size, void* d_ws, size_t ws_size,
                              hipStream_t stream)
{
  const float* p3      = (const float*)d_in[0];
  const float* p4      = (const float*)d_in[1];
  const float* p5      = (const float*)d_in[2];
  const float* p6      = (const float*)d_in[3];
  const float* p7      = (const float*)d_in[4];
  const float* cls_w   = (const float*)d_in[5];
  const float* cls_b   = (const float*)d_in[6];
  const float* cls_gw  = (const float*)d_in[7];
  const float* cls_gb  = (const float*)d_in[8];
  const float* box_w   = (const float*)d_in[9];
  const float* box_b   = (const float*)d_in[10];
  const float* box_gw  = (const float*)d_in[11];
  const float* box_gb  = (const float*)d_in[12];
  const float* score_w = (const float*)d_in[13];
  const float* score_b = (const float*)d_in[14];
  const float* pred_w  = (const float*)d_in[15];
  const float* pred_b  = (const float*)d_in[16];
  const float* iou_w   = (const float*)d_in[17];
  const float* iou_b   = (const float*)d_in[18];
  const float* scales  = (const float*)d_in[19];
  float* out = (float*)d_out;

  char* w = (char*)d_ws;
  size_t o = 0;
  auto alloc = [&](size_t b) { void* p = w + o; o += (b + 255) & ~(size_t)255; return p; };
  u16* WRC = (u16*)alloc((size_t)4*256*KTOT*2);
  u16* WRB = (u16*)alloc((size_t)4*256*KTOT*2);
  u16* WHC = (u16*)alloc((size_t)128*KTOT*2);
  u16* WHB = (u16*)alloc((size_t)128*KTOT*2);
  u16* XF  = (u16*)alloc((size_t)PP_TOT*CCH*2);   // XF..XB1 contiguous (sizes are 256B-multiples)
  u16* XC0 = (u16*)alloc((size_t)PP_TOT*CCH*2);
  u16* XC1 = (u16*)alloc((size_t)PP_TOT*CCH*2);
  u16* XB0 = (u16*)alloc((size_t)PP_TOT*CCH*2);
  u16* XB1 = (u16*)alloc((size_t)PP_TOT*CCH*2);
  float* YC = (float*)alloc((size_t)P_TOT*CCH*4);
  float* YB = (float*)alloc((size_t)P_TOT*CCH*4);
  float* ST = (float*)alloc((size_t)2*5*32*2*4);

  // zero padded activation buffers (borders must be 0) + GN stats
  hipMemsetAsync(XF, 0, (size_t)5*PP_TOT*CCH*2, stream);
  hipMemsetAsync(ST, 0, (size_t)2*5*32*2*4, stream);

  wconv<<<dim3((unsigned)(((size_t)2*4*256*KTOT + 255)/256)), 256, 0, stream>>>(cls_w, box_w, WRC, WRB);
  hconv<<<dim3((2*128*KTOT + 255)/256), 256, 0, stream>>>(score_w, pred_w, iou_w, WHC, WHB);
  feat2bf<<<dim3((P_TOT*32 + 255)/256), 256, 0, stream>>>(p3, p4, p5, p6, p7, XF);

  const u16* xci = XF; const u16* xbi = XF;
  u16* xcs[4] = {XC0, XC1, XC0, XC1};
  u16* xbs[4] = {XB0, XB1, XB0, XB1};
  for (int l = 0; l < 4; l++) {
    gemm_conv<0><<<dim3(135, 2, 2), 256, 0, stream>>>(
        xci, xbi, WRC + (size_t)l*256*KTOT, WRB + (size_t)l*256*KTOT,
        cls_b + l*256, box_b + l*256, YC, YB, ST,
        nullptr, nullptr, nullptr, nullptr);
    gn_relu<<<dim3((2*P_TOT*32 + 255)/256), 256, 0, stream>>>(
        YC, YB, ST, cls_gw + l*256, cls_gb + l*256, box_gw + l*256, box_gb + l*256,
        xcs[l], xbs[l]);
    if (l < 3) hipMemsetAsync(ST, 0, (size_t)2*5*32*2*4, stream);
    xci = xcs[l]; xbi = xbs[l];
  }
  gemm_conv<1><<<dim3(135, 1, 2), 256, 0, stream>>>(
      xci, xbi, WHC, WHB, score_b, nullptr, nullptr, nullptr, nullptr,
      pred_b, iou_b, scales, out);
}